// Round 7
// baseline (360.860 us; speedup 1.0000x reference)
//
#include <hip/hip_runtime.h>
#include <hip/hip_bf16.h>

// GraphSAGE fwd on MI355X, v6.
// v5 -> v6: (1) agg_fc un-bloated: no wf LDS staging (B-frags read from
// L2-hot WFCT), hh XOR-swizzled -> LDS 42.5K->16K, occupancy 54->~80%,
// bank conflicts ~0. (2) dispatch merging: [prep ∪ bucket] and
// [csr_build ∪ gemm1] (independent; 64KB dynamic-LDS overlay) -> 5 dispatches
// + 2 tiny memsets. (3) agg_epi persistent grid-stride.

#define N_NODES 100000
#define N_EDGES 1600000
#define NBUCK   196      // ceil(N/512)
#define BCAP    12288    // raw slots per bucket (mean 8163, +45 sigma)
#define PB_CAP  14336    // padded csr region per bucket
#define CHUNK   4096     // edges per bucket block
#define PREP_BLKS 432    // 432*256 = 110592 prep elements exactly
#define GEMM1_BLKS 782   // ceil(N/128)

typedef unsigned short u16;
typedef unsigned int u32;
typedef __bf16 bf16x8 __attribute__((ext_vector_type(8)));
typedef float  f32x4  __attribute__((ext_vector_type(4)));

__device__ __forceinline__ u16 f2b(float f) {
  unsigned x = __builtin_bit_cast(unsigned, f);
  unsigned r = x + 0x7fffu + ((x >> 16) & 1u);
  return (u16)(r >> 16);
}
__device__ __forceinline__ bf16x8 ldfrag(const u16* p) {
  uint4 u = *reinterpret_cast<const uint4*>(p);
  return __builtin_bit_cast(bf16x8, u);
}
__device__ __forceinline__ void unpack8(uint4 u, float* f) {
  f[0] = __builtin_bit_cast(float, u.x << 16);
  f[1] = __builtin_bit_cast(float, u.x & 0xffff0000u);
  f[2] = __builtin_bit_cast(float, u.y << 16);
  f[3] = __builtin_bit_cast(float, u.y & 0xffff0000u);
  f[4] = __builtin_bit_cast(float, u.z << 16);
  f[5] = __builtin_bit_cast(float, u.z & 0xffff0000u);
  f[6] = __builtin_bit_cast(float, u.w << 16);
  f[7] = __builtin_bit_cast(float, u.w & 0xffff0000u);
}
__device__ __forceinline__ uint4 pack8(const float* f) {
  uint4 u;
  u.x = (u32)f2b(f[0]) | ((u32)f2b(f[1]) << 16);
  u.y = (u32)f2b(f[2]) | ((u32)f2b(f[3]) << 16);
  u.z = (u32)f2b(f[4]) | ((u32)f2b(f[5]) << 16);
  u.w = (u32)f2b(f[6]) | ((u32)f2b(f[7]) << 16);
  return u;
}

__device__ __forceinline__ int wave_incl_scan(int x, int lane) {
#pragma unroll
  for (int d = 1; d < 64; d <<= 1) {
    int n = __shfl_up(x, d, 64);
    if (lane >= d) x += n;
  }
  return x;
}

// ================= dispatch 1: prep ∪ bucket (256 thr) =================
__device__ void prep_body(int bid, const float* __restrict__ w1s,
                          const float* __restrict__ w1n,
                          const float* __restrict__ w2s,
                          const float* __restrict__ w2n,
                          const float* __restrict__ wfc, u16* __restrict__ WT1,
                          u16* __restrict__ WT2, u16* __restrict__ WFCT) {
  int i = bid * 256 + threadIdx.x;
  if (i < 32768) {                       // WT1: [256 cols][128 k]
    int c = i >> 7, k = i & 127;
    float v = (c < 128) ? w1s[k * 128 + c] : w1n[k * 128 + (c - 128)];
    WT1[c * 128 + k] = f2b(v);
  } else if (i < 32768 + 65536) {        // WT2: [256 cols][256 k]
    int j = i - 32768;
    int c = j >> 8, k = j & 255;
    float v = (c < 128) ? w2s[k * 128 + c] : w2n[k * 128 + (c - 128)];
    WT2[c * 256 + k] = f2b(v);
  } else {                               // WFCT: [48 cols][256 k], 40..47 zero
    int j = i - 98304;
    int c = j >> 8, k = j & 255;
    float v = (c < 40) ? wfc[k * 40 + c] : 0.f;
    WFCT[c * 256 + k] = f2b(v);
  }
}

__global__ __launch_bounds__(256) void prep_bucket_kernel(
    const float* __restrict__ w1s, const float* __restrict__ w1n,
    const float* __restrict__ w2s, const float* __restrict__ w2n,
    const float* __restrict__ wfc, u16* __restrict__ WT1,
    u16* __restrict__ WT2, u16* __restrict__ WFCT,
    const int* __restrict__ src, const int* __restrict__ dst,
    int* __restrict__ cntg, u32* __restrict__ pairBuf) {
  if (blockIdx.x < PREP_BLKS) {
    prep_body(blockIdx.x, w1s, w1n, w2s, w2n, wfc, WT1, WT2, WFCT);
    return;
  }
  // ---- bucket body ----
  __shared__ unsigned hist[NBUCK];
  __shared__ unsigned gbase[NBUCK];
  __shared__ int sws[4];
  __shared__ u32 stage[CHUNK];     // 16 KB
  __shared__ int tgt[CHUNK];       // 16 KB
  const int tid = threadIdx.x, lane = tid & 63, wid = tid >> 6;
  const int e0 = (blockIdx.x - PREP_BLKS) * CHUNK;

  for (int i = tid; i < NBUCK; i += 256) hist[i] = 0u;
  __syncthreads();

  u32 myW[16];
  int myR[16], myB[16];
#pragma unroll
  for (int k = 0; k < 16; ++k) {
    int e = e0 + k * 256 + tid;
    if (e < N_EDGES) {
      unsigned d = (unsigned)dst[e];
      myW[k] = ((d & 511u) << 17) | (unsigned)src[e];
      myB[k] = (int)(d >> 9);
      myR[k] = (int)atomicAdd(&hist[myB[k]], 1u);
    } else {
      myB[k] = -1;
    }
  }
  __syncthreads();

  int cnt = (tid < NBUCK) ? (int)hist[tid] : 0;
  int inc = wave_incl_scan(cnt, lane);
  if (lane == 63) sws[wid] = inc;
  __syncthreads();
  if (wid == 0) {
    int s = (lane < 4) ? sws[lane] : 0;
    s = wave_incl_scan(s, lane);
    if (lane < 4) sws[lane] = s;
  }
  __syncthreads();
  int excl = (wid ? sws[wid - 1] : 0) + inc - cnt;
  int gofs = 0;
  if (tid < NBUCK && cnt > 0) gofs = tid * BCAP + atomicAdd(&cntg[tid], cnt);
  __syncthreads();
  if (tid < NBUCK) {
    hist[tid] = (unsigned)excl;
    gbase[tid] = (unsigned)gofs;
  }
  __syncthreads();

#pragma unroll
  for (int k = 0; k < 16; ++k) {
    if (myB[k] >= 0) {
      int slot = (int)hist[myB[k]] + myR[k];
      stage[slot] = myW[k];
      tgt[slot] = (int)gbase[myB[k]] + myR[k];
    }
  }
  __syncthreads();
  int nvalid = N_EDGES - e0;
  if (nvalid > CHUNK) nvalid = CHUNK;
  for (int i = tid; i < nvalid; i += 256) pairBuf[tgt[i]] = stage[i];
}

// ================= dispatch 2: csr_build ∪ gemm1 (512 thr, 64KB dyn LDS) =================
__device__ void csr_body(char* smem, int b, const u32* __restrict__ pairBuf,
                         const int* __restrict__ cntg, int* __restrict__ rowptr,
                         int* __restrict__ degA, int* __restrict__ csr) {
  int* lcnt = (int*)smem;            // 512
  int* lofs = lcnt + 512;            // 512
  int* sws = lofs + 512;             // 8
  int* cstage = sws + 8;             // PB_CAP
  const int tid = threadIdx.x;
  const int lane = tid & 63, wid = tid >> 6;
  int nb = cntg[b];
  if (nb > BCAP) nb = BCAP;
  const u32* pp = pairBuf + (size_t)b * BCAP;

  lcnt[tid] = 0;
  __syncthreads();
  for (int i = tid; i < nb; i += 512) atomicAdd(&lcnt[(pp[i] >> 17) & 511], 1);
  __syncthreads();
  int dg = lcnt[tid];
  int pd = (dg + 7) & ~7;
  int inc = wave_incl_scan(pd, lane);
  if (lane == 63) sws[wid] = inc;
  __syncthreads();
  if (wid == 0) {
    int s = (lane < 8) ? sws[lane] : 0;
    s = wave_incl_scan(s, lane);
    if (lane < 8) sws[lane] = s;
  }
  __syncthreads();
  int excl = (wid ? sws[wid - 1] : 0) + inc - pd;
  int ptot = sws[7];
  int node = b * 512 + tid;
  if (node < N_NODES) {
    rowptr[node] = b * PB_CAP + excl;
    degA[node] = dg;
  }
  lofs[tid] = excl;
  __syncthreads();
  for (int i = tid; i < nb; i += 512) {
    u32 pr = pp[i];
    int pos = atomicAdd(&lofs[(pr >> 17) & 511], 1);
    if (pos < PB_CAP) cstage[pos] = (int)(pr & 0x1FFFFu);
  }
  __syncthreads();
  for (int k = excl + dg; k < excl + pd; ++k)
    if (k < PB_CAP) cstage[k] = N_NODES;  // sentinel pads
  __syncthreads();
  if (ptot > PB_CAP) ptot = PB_CAP;
  for (int i = tid; i < ptot; i += 512) csr[b * PB_CAP + i] = cstage[i];
}

__device__ void gemm1_body(char* smem, int bid, const float* __restrict__ A,
                           const u16* __restrict__ WT, u16* __restrict__ Cs,
                           u16* __restrict__ Cn) {
  u16* lb = (u16*)smem;   // 64 KB: [256 cols][128 k], swizzled RB=256
  char* lbc = smem;
  const int tid = threadIdx.x;
  for (int i = tid; i < 4096; i += 512) {
    uint4 v = *reinterpret_cast<const uint4*>(WT + i * 8);
    int byte = i * 16;
    int swz = byte ^ (((byte >> 8) & 7) << 4);
    *reinterpret_cast<uint4*>(lbc + swz) = v;
  }

  const int w = tid >> 6, lane = tid & 63;
  const int lrow = lane & 15, lk = lane >> 4;
  const int xr = (lrow & 7) << 4;
  const int rbase = bid * 128 + w * 16;

  bf16x8 af[4];
  {
    int r = rbase + lrow;
    if (r >= N_NODES) r = N_NODES - 1;
    const float* ap = A + (size_t)r * 128 + lk * 8;
#pragma unroll
    for (int ks = 0; ks < 4; ++ks) {
      float4 f0 = *reinterpret_cast<const float4*>(ap + ks * 32);
      float4 f1 = *reinterpret_cast<const float4*>(ap + ks * 32 + 4);
      float f[8] = {f0.x, f0.y, f0.z, f0.w, f1.x, f1.y, f1.z, f1.w};
      af[ks] = __builtin_bit_cast(bf16x8, pack8(f));
    }
  }
  __syncthreads();

  f32x4 acc[16];
#pragma unroll
  for (int ct = 0; ct < 16; ++ct) acc[ct] = f32x4{0.f, 0.f, 0.f, 0.f};
#pragma unroll
  for (int ks = 0; ks < 4; ++ks) {
#pragma unroll
    for (int ct = 0; ct < 16; ++ct) {
      int byte = (ct * 16 + lrow) * 256 + ks * 64 + lk * 16;
      bf16x8 b = __builtin_bit_cast(
          bf16x8, *reinterpret_cast<const uint4*>(lbc + (byte ^ xr)));
      acc[ct] = __builtin_amdgcn_mfma_f32_16x16x32_bf16(af[ks], b, acc[ct], 0, 0, 0);
    }
  }
#pragma unroll
  for (int j = 0; j < 4; ++j) {
    int r = rbase + lk * 4 + j;
    if (r < N_NODES) {
      u16* cs = Cs + (size_t)r * 128 + lrow;
      u16* cn = Cn + (size_t)r * 128 + lrow;
#pragma unroll
      for (int ct = 0; ct < 8; ++ct) cs[ct * 16] = f2b(acc[ct][j]);
#pragma unroll
      for (int ct = 0; ct < 8; ++ct) cn[ct * 16] = f2b(acc[8 + ct][j]);
    }
  }
}

__global__ __launch_bounds__(512) void csr_gemm1_kernel(
    const u32* __restrict__ pairBuf, const int* __restrict__ cntg,
    int* __restrict__ rowptr, int* __restrict__ degA, int* __restrict__ csr,
    const float* __restrict__ A, const u16* __restrict__ WT,
    u16* __restrict__ Cs, u16* __restrict__ Cn) {
  extern __shared__ char smem[];
  if (blockIdx.x < NBUCK) {
    csr_body(smem, blockIdx.x, pairBuf, cntg, rowptr, degA, csr);
  } else {
    gemm1_body(smem, blockIdx.x - NBUCK, A, WT, Cs, Cn);
  }
}

// ================= shared aggregation helper (one wave, one node) =================
__device__ __forceinline__ void agg_node(
    const u16* __restrict__ Xs, const u16* __restrict__ Xn,
    const int* __restrict__ rowptr, const int* __restrict__ degA,
    const int* __restrict__ csr, const float* __restrict__ bs,
    const float* __restrict__ bn, int node, int g, int lc,
    float* sf, float* nf) {
  int beg = rowptr[node], dg = degA[node];
  int cnt = (dg + 7) & ~7;
  float acc[8] = {0.f, 0.f, 0.f, 0.f, 0.f, 0.f, 0.f, 0.f};
  const u16* colbase = Xn + lc * 8;
  const int* cp = csr + beg;
  for (int j = 0; j < cnt; j += 8) {
    int s0 = cp[j + g];
    int s1 = cp[j + 4 + g];
    uint4 u0 = *reinterpret_cast<const uint4*>(colbase + (size_t)s0 * 128);
    uint4 u1 = *reinterpret_cast<const uint4*>(colbase + (size_t)s1 * 128);
    float f0[8], f1[8];
    unpack8(u0, f0);
    unpack8(u1, f1);
#pragma unroll
    for (int i = 0; i < 8; ++i) acc[i] += f0[i] + f1[i];
  }
#pragma unroll
  for (int i = 0; i < 8; ++i) {
    acc[i] += __shfl_xor(acc[i], 32, 64);
    acc[i] += __shfl_xor(acc[i], 16, 64);
  }
  float inv = 1.f / (float)(dg > 0 ? dg : 1);
  uint4 sv4 = *reinterpret_cast<const uint4*>(Xs + (size_t)node * 128 + lc * 8);
  unpack8(sv4, sf);
  float4 b0 = *reinterpret_cast<const float4*>(bs + lc * 8);
  float4 b1 = *reinterpret_cast<const float4*>(bs + lc * 8 + 4);
  float4 c0 = *reinterpret_cast<const float4*>(bn + lc * 8);
  float4 c1 = *reinterpret_cast<const float4*>(bn + lc * 8 + 4);
  float bsv[8] = {b0.x, b0.y, b0.z, b0.w, b1.x, b1.y, b1.z, b1.w};
  float bnv[8] = {c0.x, c0.y, c0.z, c0.w, c1.x, c1.y, c1.z, c1.w};
  float ss = 0.f;
#pragma unroll
  for (int i = 0; i < 8; ++i) {
    sf[i] = fmaxf(sf[i] + bsv[i], 0.f);
    nf[i] = fmaxf(acc[i] * inv + bnv[i], 0.f);
    ss += sf[i] * sf[i] + nf[i] * nf[i];
  }
  ss += __shfl_xor(ss, 1, 64);
  ss += __shfl_xor(ss, 2, 64);
  ss += __shfl_xor(ss, 4, 64);
  ss += __shfl_xor(ss, 8, 64);
  float sc = 1.f / fmaxf(sqrtf(ss), 1e-12f);
#pragma unroll
  for (int i = 0; i < 8; ++i) {
    sf[i] *= sc;
    nf[i] *= sc;
  }
}

// ================= dispatch 3: agg1 (persistent grid-stride) =================
__global__ __launch_bounds__(256) void agg_epi_kernel(
    const u16* __restrict__ Xs, const u16* __restrict__ Xn,
    const int* __restrict__ rowptr, const int* __restrict__ degA,
    const int* __restrict__ csr, const float* __restrict__ bs,
    const float* __restrict__ bn, u16* __restrict__ H) {
  const int lane = threadIdx.x & 63;
  const int g = lane >> 4, lc = lane & 15;
  const int wave0 = blockIdx.x * 4 + (threadIdx.x >> 6);
  const int stride = gridDim.x * 4;
  for (int node = wave0; node < N_NODES; node += stride) {
    float sf[8], nf[8];
    agg_node(Xs, Xn, rowptr, degA, csr, bs, bn, node, g, lc, sf, nf);
    if (g == 0) {
      *reinterpret_cast<uint4*>(H + (size_t)node * 256 + lc * 8) = pack8(sf);
    } else if (g == 1) {
      *reinterpret_cast<uint4*>(H + (size_t)node * 256 + 128 + lc * 8) = pack8(nf);
    }
  }
}

// ================= dispatch 4: gemm2 =================
__global__ __launch_bounds__(512) void gemm2_kernel(
    const u16* __restrict__ A, const u16* __restrict__ WT,
    u16* __restrict__ Cs, u16* __restrict__ Cn) {
  __shared__ u16 lb[128 * 256];   // 64 KB: [128 cols][256 k], swizzled RB=512
  char* lbc = reinterpret_cast<char*>(lb);
  const int tid = threadIdx.x;
  const int w = tid >> 6, lane = tid & 63;
  const int lrow = lane & 15, lk = lane >> 4;
  const int xr = (lrow & 7) << 4;
  const int rbase = blockIdx.x * 128 + w * 16;

  bf16x8 af[8];
  {
    int r = rbase + lrow;
    if (r >= N_NODES) r = N_NODES - 1;
    const u16* ap = A + (size_t)r * 256 + lk * 8;
#pragma unroll
    for (int ks = 0; ks < 8; ++ks) af[ks] = ldfrag(ap + ks * 32);
  }

#pragma unroll
  for (int half = 0; half < 2; ++half) {
    const u16* Wsrc = WT + (size_t)half * 128 * 256;
    for (int i = tid; i < 4096; i += 512) {
      uint4 v = *reinterpret_cast<const uint4*>(Wsrc + i * 8);
      int byte = i * 16;
      int swz = byte ^ (((byte >> 9) & 7) << 4);
      *reinterpret_cast<uint4*>(lbc + swz) = v;
    }
    __syncthreads();

    f32x4 acc[8];
#pragma unroll
    for (int ct = 0; ct < 8; ++ct) acc[ct] = f32x4{0.f, 0.f, 0.f, 0.f};
#pragma unroll
    for (int ks = 0; ks < 8; ++ks) {
#pragma unroll
      for (int ct = 0; ct < 8; ++ct) {
        int byte = (ct * 16 + lrow) * 512 + ks * 64 + lk * 16;
        bf16x8 b = __builtin_bit_cast(
            bf16x8, *reinterpret_cast<const uint4*>(lbc + (byte ^ xr)));
        acc[ct] = __builtin_amdgcn_mfma_f32_16x16x32_bf16(af[ks], b, acc[ct], 0, 0, 0);
      }
    }
    u16* __restrict__ Cout = half ? Cn : Cs;
#pragma unroll
    for (int j = 0; j < 4; ++j) {
      int r = rbase + lk * 4 + j;
      if (r < N_NODES) {
        u16* cp = Cout + (size_t)r * 128 + lrow;
#pragma unroll
        for (int ct = 0; ct < 8; ++ct) cp[ct * 16] = f2b(acc[ct][j]);
      }
    }
    __syncthreads();
  }
}

// ================= dispatch 5: agg2 + fused FC =================
// 512 thr = 8 waves, 32 nodes/block. hh XOR-swizzled (row&7)<<4; FC B-frags
// read directly from L2-hot WFCT. LDS = 16 KB.
__global__ __launch_bounds__(512) void agg_fc_kernel(
    const u16* __restrict__ Xs, const u16* __restrict__ Xn,
    const int* __restrict__ rowptr, const int* __restrict__ degA,
    const int* __restrict__ csr, const float* __restrict__ bs,
    const float* __restrict__ bn, const u16* __restrict__ WFCT,
    const float* __restrict__ bfc, float* __restrict__ Out) {
  __shared__ u16 hh[32 * 256];   // 16 KB, swizzled: byte = r*512 + (c ^ ((r&7)<<4))
  char* hhb = reinterpret_cast<char*>(hh);
  const int tid = threadIdx.x, w = tid >> 6, lane = tid & 63;
  const int g = lane >> 4, lc = lane & 15;
  const int nb0 = blockIdx.x * 32;

  // aggregate 4 nodes per wave into hh
  for (int t = 0; t < 4; ++t) {
    int r = w * 4 + t;
    int node = nb0 + r;
    int xr_r = (r & 7) << 4;
    uint4 val;
    int cbyte;
    if (node < N_NODES) {
      float sf[8], nf[8];
      agg_node(Xs, Xn, rowptr, degA, csr, bs, bn, node, g, lc, sf, nf);
      val = (g == 0) ? pack8(sf) : pack8(nf);
    } else {
      val = uint4{0u, 0u, 0u, 0u};
    }
    if (g == 0) {
      cbyte = (lc * 16) ^ xr_r;
      *reinterpret_cast<uint4*>(hhb + r * 512 + cbyte) = val;
    } else if (g == 1) {
      cbyte = 256 + ((lc * 16) ^ xr_r);
      *reinterpret_cast<uint4*>(hhb + r * 512 + cbyte) = val;
    }
  }
  __syncthreads();

  // fc: wave task (rt = w&1, cg = w>>1), cg<3 covers 48 cols
  const int rt = w & 1, cg = w >> 1;
  if (cg < 3) {
    const int lrow = lane & 15, lk = lane >> 4;
    const int arow = rt * 16 + lrow;
    const int xr_a = (arow & 7) << 4;
    f32x4 acc = {0.f, 0.f, 0.f, 0.f};
#pragma unroll
    for (int ks = 0; ks < 8; ++ks) {
      int cbyte = (ks * 64 + lk * 16) ^ xr_a;
      bf16x8 a = __builtin_bit_cast(
          bf16x8, *reinterpret_cast<const uint4*>(hhb + arow * 512 + cbyte));
      bf16x8 b = ldfrag(WFCT + (size_t)(cg * 16 + lrow) * 256 + ks * 32 + lk * 8);
      acc = __builtin_amdgcn_mfma_f32_16x16x32_bf16(a, b, acc, 0, 0, 0);
    }
#pragma unroll
    for (int j = 0; j < 4; ++j) {
      int row = nb0 + rt * 16 + lk * 4 + j;
      int col = cg * 16 + lrow;
      if (row < N_NODES && col < 40) Out[(size_t)row * 40 + col] = acc[j] + bfc[col];
    }
  }
}

// ================= launch =================
extern "C" void kernel_launch(void* const* d_in, const int* in_sizes, int n_in,
                              void* d_out, int out_size, void* d_ws, size_t ws_size,
                              hipStream_t stream) {
  const float* x = (const float*)d_in[0];
  const int* src = (const int*)d_in[1];
  const int* dst = (const int*)d_in[2];
  const float* w1s = (const float*)d_in[3];
  const float* b1s = (const float*)d_in[4];
  const float* w1n = (const float*)d_in[5];
  const float* b1n = (const float*)d_in[6];
  const float* w2s = (const float*)d_in[7];
  const float* b2s = (const float*)d_in[8];
  const float* w2n = (const float*)d_in[9];
  const float* b2n = (const float*)d_in[10];
  const float* wfc = (const float*)d_in[11];
  const float* bfc = (const float*)d_in[12];
  float* out = (float*)d_out;

  char* p = (char*)d_ws;
  auto alloc = [&](size_t bytes) {
    char* r = p;
    p += (bytes + 255) & ~(size_t)255;
    return r;
  };
  u16* XWs = (u16*)alloc((size_t)N_NODES * 128 * 2);        // 25.6 MB
  u16* XWn = (u16*)alloc(((size_t)N_NODES + 1) * 128 * 2);  // 25.6 MB (+sentinel)
  u16* h1 = (u16*)alloc((size_t)N_NODES * 256 * 2);         // 51.2 MB
  u16* WT1 = (u16*)alloc(32768 * 2);
  u16* WT2 = (u16*)alloc(65536 * 2);
  u16* WFCT = (u16*)alloc(12288 * 2);
  u32* pairBuf = (u32*)alloc((size_t)NBUCK * BCAP * 4);     // 9.6 MB
  int* cntg = (int*)alloc(NBUCK * 4);
  int* rowptr = (int*)alloc((size_t)N_NODES * 4);
  int* degA = (int*)alloc((size_t)N_NODES * 4);
  int* csr = (int*)alloc((size_t)NBUCK * PB_CAP * 4);       // 11.2 MB

  hipMemsetAsync(cntg, 0, NBUCK * 4, stream);
  hipMemsetAsync(XWn + (size_t)N_NODES * 128, 0, 256, stream);

  prep_bucket_kernel<<<PREP_BLKS + 391, 256, 0, stream>>>(
      w1s, w1n, w2s, w2n, wfc, WT1, WT2, WFCT, src, dst, cntg, pairBuf);
  csr_gemm1_kernel<<<NBUCK + GEMM1_BLKS, 512, 65536, stream>>>(
      pairBuf, cntg, rowptr, degA, csr, x, WT1, XWs, XWn);
  agg_epi_kernel<<<2048, 256, 0, stream>>>(XWs, XWn, rowptr, degA, csr, b1s, b1n, h1);
  gemm2_kernel<<<GEMM1_BLKS, 512, 0, stream>>>(h1, WT2, XWs, XWn);
  agg_fc_kernel<<<3125, 512, 0, stream>>>(XWs, XWn, rowptr, degA, csr, b2s, b2n,
                                          WFCT, bfc, out);
}